// Round 11
// baseline (212.933 us; speedup 1.0000x reference)
//
#include <hip/hip_runtime.h>

typedef float f32x4 __attribute__((ext_vector_type(4)));

constexpr int EMB    = 300;
constexpr int EMB4   = 75;     // EMB/4 (8-B bf16 chunks per row)
constexpr int HIDDEN = 512;
constexpr int SEQ    = 512;
constexpr int BATCH  = 1024;
constexpr int VOCAB  = 50000;
constexpr int NBUK   = 32;     // vocab buckets
constexpr int BDIV   = 1563;   // ceil(50000/32)
constexpr int PB     = 4;      // batches per pool claim
constexpr int NX     = 8;      // slots == XCDs
constexpr int NGRP   = BATCH / PB;      // 256 claims per slot
constexpr int GMLP   = 8;      // batches per mlp block
constexpr int NCONV  = 1792;   // convert blocks inside prep
constexpr int ELEM4  = VOCAB * EMB / 4; // float4s in emb

__device__ __forceinline__ unsigned short f2bf(float x) {   // RNE f32->bf16
    unsigned u = __float_as_uint(x);
    u += 0x7fffu + ((u >> 16) & 1u);
    return (unsigned short)(u >> 16);
}

__device__ __forceinline__ f32x4 bf4up(uint2 u) {   // 4 bf16 -> f32x4
    f32x4 r;
    r.x = __uint_as_float(u.x << 16);
    r.y = __uint_as_float(u.x & 0xffff0000u);
    r.z = __uint_as_float(u.y << 16);
    r.w = __uint_as_float(u.y & 0xffff0000u);
    return r;
}

// ---------------- Kernel 1: prep = bucketize + f32->bf16 convert + tickets ---
__global__ __launch_bounds__(256) void prep_kernel(
    const int* __restrict__ text,      // [SEQ, BATCH]
    const int* __restrict__ lengths,   // [BATCH]
    const float* __restrict__ emb,     // [VOCAB, EMB]
    int* __restrict__ btok,            // [BATCH, SEQ]
    int* __restrict__ boff,            // [BATCH, NBUK+1]
    unsigned short* __restrict__ ebf,  // [VOCAB, EMB] bf16
    int* __restrict__ tickets,         // [NX]
    int doConv)
{
    __shared__ int4 tstage[SEQ];           // 8 KB
    __shared__ int  hist[4][8][NBUK + 2];

    const int tid = threadIdx.x;

    if (blockIdx.x >= 256) {               // ---- convert lane ----
        if (!doConv) return;
        if (blockIdx.x == 256 && tid < NX) tickets[tid] = 0;
        const float4* src = (const float4*)emb;
        ushort4*      dst = (ushort4*)ebf;
        const int gtid = (blockIdx.x - 256) * 256 + tid;
        for (int i = gtid; i < ELEM4; i += NCONV * 256) {
            const float4 v = src[i];
            ushort4 o;
            o.x = f2bf(v.x); o.y = f2bf(v.y);
            o.z = f2bf(v.z); o.w = f2bf(v.w);
            dst[i] = o;
        }
        return;
    }

    // ---- bucketize lane (verified since R9; bitwise-stable output) ----
    const int wave = tid >> 6;
    const int lane = tid & 63;
    const int b0   = blockIdx.x * 4;
    const int b    = b0 + wave;
    const int len  = lengths[b];
    const unsigned long long lt = (1ull << lane) - 1ull;

    for (int s = tid; s < SEQ; s += 256)
        tstage[s] = *(const int4*)&text[(size_t)s * BATCH + b0];
    for (int i = tid; i < 4 * 8 * (NBUK + 2); i += 256)
        ((int*)hist)[i] = 0;
    __syncthreads();

    int tokv[8], kv[8], rkv[8];
#pragma unroll
    for (int c = 0; c < 8; ++c) {
        const int s      = c * 64 + lane;
        const bool valid = s < len;
        const int tok = valid ? ((const int*)&tstage[s])[wave] : 0;
        const int k   = valid ? tok / BDIV : NBUK;
        unsigned long long mm = ~0ull;
#pragma unroll
        for (int bit = 0; bit < 6; ++bit) {
            const unsigned long long bl = __ballot((k >> bit) & 1);
            mm &= ((k >> bit) & 1) ? bl : ~bl;
        }
        const int rk = __popcll(mm & lt);
        tokv[c] = tok; kv[c] = k; rkv[c] = rk;
        if (valid && rk == 0) hist[wave][c][k] = __popcll(mm);
    }
    __syncthreads();

    int tot = 0;
    if (lane < NBUK) {
#pragma unroll
        for (int c = 0; c < 8; ++c) {
            const int t = hist[wave][c][lane];
            hist[wave][c][lane] = tot;
            tot += t;
        }
    }
    int incl = tot;
#pragma unroll
    for (int off = 1; off < 32; off <<= 1) {
        const int v = __shfl_up(incl, off);
        if (lane >= off && lane < NBUK) incl += v;
    }
    const int excl = incl - tot;
    if (lane < NBUK)      boff[b * (NBUK + 1) + lane] = excl;
    if (lane == NBUK - 1) boff[b * (NBUK + 1) + NBUK] = incl;
    __syncthreads();

#pragma unroll
    for (int c = 0; c < 8; ++c) {
        const int s  = c * 64 + lane;
        const int k  = kv[c];
        const int bb = __shfl(excl, k);
        const int pos = bb + hist[wave][c][k] + rkv[c];
        if (s < len) btok[(size_t)b * SEQ + pos] = tokv[c];
    }
}

// ---------------- Kernel 2: pool — XCD-pinned dynamic claiming ---------------
// Block reads its PHYSICAL XCD id (s_getreg HW_REG_XCC_ID) and claims
// batch-groups from the ticket of the matching vocab slot, so slot x's
// 3.75 MB bf16 slice is gathered only from XCD x's L2. Steal loop (t>0)
// guarantees completion under any dispatch; results are deterministic since
// each (group, slot) partial is a fixed token set in fixed order.
__global__ __launch_bounds__(320) void pool_kernel(
    const int* __restrict__ btok,      // [BATCH, SEQ] bucket-grouped
    const int* __restrict__ boff,      // [BATCH, NBUK+1]
    const unsigned short* __restrict__ ebf, // [VOCAB, EMB] bf16
    float* __restrict__ partial,       // [NX, BATCH, EMB]
    int* __restrict__ tickets)         // [NX]
{
    __shared__ int toks[PB][SEQ];      // 8 KB
    __shared__ int seg[PB][2];
    __shared__ int claimsh;

    int xcc;
    asm volatile("s_getreg_b32 %0, hwreg(HW_REG_XCC_ID)" : "=s"(xcc));
    xcc &= (NX - 1);

    const int tid = threadIdx.x;
    const int grp = tid / 80;          // 0..3 -> batch within claim
    const int c   = tid % 80;          // 0..74 active = uint2 chunk of row
    const int NJ  = NBUK / NX;         // 4 buckets per slot

    for (int t = 0; t < NX; ++t) {
        const int x = (xcc + t) & (NX - 1);
        while (true) {
            __syncthreads();
            if (tid == 0) claimsh = atomicAdd(&tickets[x], 1);
            __syncthreads();
            const int g = claimsh;
            if (g >= NGRP) break;
            const int b0 = g * PB;

            if (tid < PB) {
                const int b  = b0 + tid;
                const int lo = boff[b * (NBUK + 1) + x * NJ];
                const int hi = boff[b * (NBUK + 1) + x * NJ + NJ];
                seg[tid][0] = lo;
                seg[tid][1] = hi - lo;
            }
            __syncthreads();
            for (int g2 = 0; g2 < PB; ++g2) {
                const int lo = seg[g2][0], n = seg[g2][1];
                for (int tt = tid; tt < n; tt += 320)
                    toks[g2][tt] = btok[(size_t)(b0 + g2) * SEQ + lo + tt];
            }
            __syncthreads();

            if (c < EMB4) {
                const int n = seg[grp][1];
                const uint2* e2 = (const uint2*)ebf;   // row stride EMB4
                f32x4 A = {0.f, 0.f, 0.f, 0.f};
                f32x4 B = A;
                int i = 0;
                for (; i + 4 <= n; i += 4) {
                    const int4 t4 = *(const int4*)&toks[grp][i];
                    const uint2 u0 = e2[(size_t)t4.x * EMB4 + c];
                    const uint2 u1 = e2[(size_t)t4.y * EMB4 + c];
                    const uint2 u2 = e2[(size_t)t4.z * EMB4 + c];
                    const uint2 u3 = e2[(size_t)t4.w * EMB4 + c];
                    A += bf4up(u0) + bf4up(u1);
                    B += bf4up(u2) + bf4up(u3);
                }
                for (; i < n; ++i)
                    A += bf4up(e2[(size_t)toks[grp][i] * EMB4 + c]);
                A += B;
                f32x4* dst = (f32x4*)(partial + ((size_t)x * BATCH + b0 + grp) * EMB) + c;
                __builtin_nontemporal_store(A, dst);   // don't evict the slice
            }
        }
    }
}

// ---------------- Kernel 3: fused combine + fc1 + relu + fc2 (R10) -----------
template<int NXT>
__global__ __launch_bounds__(512) void mlp_kernel(
    const float* __restrict__ partial, // [NXT, BATCH, EMB]
    const int* __restrict__ lengths,   // [BATCH]
    const float* __restrict__ W1,      // [EMB, HIDDEN]
    const float* __restrict__ b1,      // [HIDDEN]
    const float* __restrict__ W2,      // [HIDDEN, 2]
    const float* __restrict__ b2,      // [2]
    float* __restrict__ out)           // [BATCH, 2]
{
    __shared__ f32x4 pQ[GMLP / 4][EMB];    // 9.6 KB
    __shared__ float hsh[GMLP][HIDDEN];    // 16 KB

    const int b0  = blockIdx.x * GMLP;
    const int tid = threadIdx.x;

    float* pQf = (float*)pQ;
    for (int i = tid; i < EMB * GMLP; i += 512) {
        const int g = i / EMB;
        const int e = i - g * EMB;
        float s = 0.f;
#pragma unroll
        for (int xx = 0; xx < NXT; ++xx)
            s += partial[((size_t)xx * BATCH + b0 + g) * EMB + e];
        pQf[((g >> 2) * EMB + e) * 4 + (g & 3)] = s / (float)lengths[b0 + g];
    }
    __syncthreads();

    const int j = tid;                     // HIDDEN == blockDim
    const float bias = b1[j];
    f32x4 acc0 = {bias, bias, bias, bias};
    f32x4 acc1 = acc0;

#pragma unroll 10
    for (int e = 0; e < EMB; ++e) {
        const float w = W1[(size_t)e * HIDDEN + j];
        acc0 += pQ[0][e] * w;
        acc1 += pQ[1][e] * w;
    }
    hsh[0][j] = fmaxf(acc0.x, 0.f);
    hsh[1][j] = fmaxf(acc0.y, 0.f);
    hsh[2][j] = fmaxf(acc0.z, 0.f);
    hsh[3][j] = fmaxf(acc0.w, 0.f);
    hsh[4][j] = fmaxf(acc1.x, 0.f);
    hsh[5][j] = fmaxf(acc1.y, 0.f);
    hsh[6][j] = fmaxf(acc1.z, 0.f);
    hsh[7][j] = fmaxf(acc1.w, 0.f);
    __syncthreads();

    const int w    = tid >> 6;             // 0..7 -> batch row
    const int lane = tid & 63;
    const f32x4* W2v = (const f32x4*)W2;
    float s0 = 0.f, s1 = 0.f;
#pragma unroll
    for (int q = 0; q < 2; ++q) {
        const int cc = lane + q * 64;
        const f32x4 hv = *(const f32x4*)&hsh[w][4 * cc];
        const f32x4 wA = W2v[2 * cc + 0];
        const f32x4 wB = W2v[2 * cc + 1];
        s0 += hv.x * wA.x + hv.y * wA.z + hv.z * wB.x + hv.w * wB.z;
        s1 += hv.x * wA.y + hv.y * wA.w + hv.z * wB.y + hv.w * wB.w;
    }
#pragma unroll
    for (int off = 32; off > 0; off >>= 1) {
        s0 += __shfl_down(s0, off);
        s1 += __shfl_down(s1, off);
    }
    if (lane == 0) {
        out[(b0 + w) * 2 + 0] = s0 + b2[0];
        out[(b0 + w) * 2 + 1] = s1 + b2[1];
    }
}

// ---------------- Fallback pool (tiny ws): naive f32 gather ------------------
__global__ __launch_bounds__(320) void naive_pool(
    const int* __restrict__ text, const int* __restrict__ lengths,
    const float* __restrict__ emb, float* __restrict__ pooled)
{
    __shared__ int toks[SEQ];
    const int b = blockIdx.x;
    const int len = lengths[b];
    for (int s = threadIdx.x; s < len; s += 320)
        toks[s] = text[(size_t)s * BATCH + b];
    __syncthreads();
    const int e = threadIdx.x;
    if (e < EMB) {
        float a = 0.f;
        for (int s = 0; s < len; ++s)
            a += emb[(size_t)toks[s] * EMB + e];
        pooled[(size_t)b * EMB + e] = a;   // mlp<1> divides by len
    }
}

extern "C" void kernel_launch(void* const* d_in, const int* in_sizes, int n_in,
                              void* d_out, int out_size, void* d_ws, size_t ws_size,
                              hipStream_t stream) {
    const int*   text    = (const int*)d_in[0];
    const int*   lengths = (const int*)d_in[1];
    const float* emb     = (const float*)d_in[2];
    const float* W1      = (const float*)d_in[3];
    const float* b1      = (const float*)d_in[4];
    const float* W2      = (const float*)d_in[5];
    const float* b2      = (const float*)d_in[6];
    float*       out     = (float*)d_out;

    char* ws = (char*)d_ws;
    const size_t btokBytes = (size_t)BATCH * SEQ * sizeof(int);            // 2 MB
    const size_t boffBytes = (size_t)BATCH * (NBUK + 1) * sizeof(int);     // 132 KB
    const size_t tickBytes = 64;
    const size_t ebfBytes  = (size_t)VOCAB * EMB * sizeof(unsigned short); // 30 MB
    const size_t poolBytes = (size_t)BATCH * EMB * sizeof(float);          // 1.2 MB

    int* btok = (int*)ws;
    int* boff = (int*)(ws + btokBytes);
    size_t off = btokBytes + boffBytes;
    off = (off + 63) & ~(size_t)63;
    int* tickets = (int*)(ws + off);
    off += tickBytes;
    unsigned short* ebf = (unsigned short*)(ws + off);
    float* partial = (float*)(ws + off + ebfBytes);

    const size_t need = off + ebfBytes + (size_t)NX * poolBytes;   // ~42 MB

    if (ws_size >= need) {
        prep_kernel<<<256 + NCONV, 256, 0, stream>>>(
            text, lengths, emb, btok, boff, ebf, tickets, 1);
        pool_kernel<<<1536, 320, 0, stream>>>(btok, boff, ebf, partial, tickets);
        mlp_kernel<8><<<BATCH / GMLP, 512, 0, stream>>>(
            partial, lengths, W1, b1, W2, b2, out);
    } else {
        float* pooled = (float*)ws;    // [BATCH, EMB], 1.2 MB
        naive_pool<<<BATCH, 320, 0, stream>>>(text, lengths, emb, pooled);
        mlp_kernel<1><<<BATCH / GMLP, 512, 0, stream>>>(
            pooled, lengths, W1, b1, W2, b2, out);
    }
}

// Round 12
// 63.404 us; speedup vs baseline: 3.3583x; 3.3583x over previous
//
#include <hip/hip_runtime.h>

typedef float f32x4 __attribute__((ext_vector_type(4)));

constexpr int EMB    = 300;
constexpr int EMB4   = 75;     // 8-B bf16 chunks per row
constexpr int HIDDEN = 512;
constexpr int SEQ    = 512;
constexpr int BATCH  = 1024;
constexpr int VOCAB  = 50000;
constexpr int NBUK   = 32;     // vocab buckets
constexpr int BDIV   = 1563;   // ceil(50000/32)
constexpr int NX     = 8;      // vocab slots (buckets NJ=4 each)
constexpr int GMLP   = 8;      // batches per mlp block
constexpr int NCONV  = 1792;   // convert blocks inside prep
constexpr int ELEM4  = VOCAB * EMB / 4;   // float4s in emb

__device__ __forceinline__ unsigned short f2bf(float x) {   // RNE f32->bf16
    unsigned u = __float_as_uint(x);
    u += 0x7fffu + ((u >> 16) & 1u);
    return (unsigned short)(u >> 16);
}

__device__ __forceinline__ f32x4 bf4up(uint2 u) {   // 4 bf16 -> f32x4
    f32x4 r;
    r.x = __uint_as_float(u.x << 16);
    r.y = __uint_as_float(u.x & 0xffff0000u);
    r.z = __uint_as_float(u.y << 16);
    r.w = __uint_as_float(u.y & 0xffff0000u);
    return r;
}

// ---------------- Kernel 1: prep = bucketize + f32->bf16 convert (R10) -------
__global__ __launch_bounds__(256) void prep_kernel(
    const int* __restrict__ text,      // [SEQ, BATCH]
    const int* __restrict__ lengths,   // [BATCH]
    const float* __restrict__ emb,     // [VOCAB, EMB]
    int* __restrict__ btok,            // [BATCH, SEQ]
    int* __restrict__ boff,            // [BATCH, NBUK+1]
    unsigned short* __restrict__ ebf,  // [VOCAB, EMB] bf16
    int doConv)
{
    __shared__ int4 tstage[SEQ];           // 8 KB
    __shared__ int  hist[4][8][NBUK + 2];

    const int tid = threadIdx.x;

    if (blockIdx.x >= 256) {               // ---- convert lane ----
        if (!doConv) return;
        const float4* src = (const float4*)emb;
        ushort4*      dst = (ushort4*)ebf;
        const int gtid = (blockIdx.x - 256) * 256 + tid;
        for (int i = gtid; i < ELEM4; i += NCONV * 256) {
            const float4 v = src[i];
            ushort4 o;
            o.x = f2bf(v.x); o.y = f2bf(v.y);
            o.z = f2bf(v.z); o.w = f2bf(v.w);
            dst[i] = o;
        }
        return;
    }

    // ---- bucketize lane (verified since R9; bitwise-stable output) ----
    const int wave = tid >> 6;
    const int lane = tid & 63;
    const int b0   = blockIdx.x * 4;
    const int b    = b0 + wave;
    const int len  = lengths[b];
    const unsigned long long lt = (1ull << lane) - 1ull;

    for (int s = tid; s < SEQ; s += 256)
        tstage[s] = *(const int4*)&text[(size_t)s * BATCH + b0];
    for (int i = tid; i < 4 * 8 * (NBUK + 2); i += 256)
        ((int*)hist)[i] = 0;
    __syncthreads();

    int tokv[8], kv[8], rkv[8];
#pragma unroll
    for (int c = 0; c < 8; ++c) {
        const int s      = c * 64 + lane;
        const bool valid = s < len;
        const int tok = valid ? ((const int*)&tstage[s])[wave] : 0;
        const int k   = valid ? tok / BDIV : NBUK;
        unsigned long long mm = ~0ull;
#pragma unroll
        for (int bit = 0; bit < 6; ++bit) {
            const unsigned long long bl = __ballot((k >> bit) & 1);
            mm &= ((k >> bit) & 1) ? bl : ~bl;
        }
        const int rk = __popcll(mm & lt);
        tokv[c] = tok; kv[c] = k; rkv[c] = rk;
        if (valid && rk == 0) hist[wave][c][k] = __popcll(mm);
    }
    __syncthreads();

    int tot = 0;
    if (lane < NBUK) {
#pragma unroll
        for (int c = 0; c < 8; ++c) {
            const int t = hist[wave][c][lane];
            hist[wave][c][lane] = tot;
            tot += t;
        }
    }
    int incl = tot;
#pragma unroll
    for (int off = 1; off < 32; off <<= 1) {
        const int v = __shfl_up(incl, off);
        if (lane >= off && lane < NBUK) incl += v;
    }
    const int excl = incl - tot;
    if (lane < NBUK)      boff[b * (NBUK + 1) + lane] = excl;
    if (lane == NBUK - 1) boff[b * (NBUK + 1) + NBUK] = incl;
    __syncthreads();

#pragma unroll
    for (int c = 0; c < 8; ++c) {
        const int s  = c * 64 + lane;
        const int k  = kv[c];
        const int bb = __shfl(excl, k);
        const int pos = bb + hist[wave][c][k] + rkv[c];
        if (s < len) btok[(size_t)b * SEQ + pos] = tokv[c];
    }
}

// ---------------- Kernel 2: pool — wave-autonomous, barrier-free -------------
// Grid 2048 x 256 thr = 8 blocks/CU: ALL blocks co-resident (zero drain tail).
// One wave = one (batch, slot) segment. Wave stages its tokens into its own
// LDS region (no __syncthreads anywhere). Lane L owns 8-B chunk L of the
// 600-B bf16 row; lanes 0..10 also own chunks 64..74. 4-row unrolled
// independent loads; f32 accumulate; unconditional partial write (zeros for
// empty segments — ws is poisoned).
__global__ __launch_bounds__(256) void pool_kernel(
    const int* __restrict__ btok,      // [BATCH, SEQ] bucket-grouped
    const int* __restrict__ boff,      // [BATCH, NBUK+1]
    const unsigned short* __restrict__ ebf, // [VOCAB, EMB] bf16
    float* __restrict__ partial)       // [NX, BATCH, EMB]
{
    __shared__ int toks[4][SEQ];       // 8 KB, wave-private rows

    const int wave = threadIdx.x >> 6;
    const int lane = threadIdx.x & 63;
    const int x    = blockIdx.x & (NX - 1);          // slot ~ dispatch round-robin
    const int b    = (blockIdx.x >> 3) * 4 + wave;   // batch
    const int NJ   = NBUK / NX;                      // 4 buckets per slot

    const int lo = boff[b * (NBUK + 1) + x * NJ];        // broadcast load
    const int hi = boff[b * (NBUK + 1) + x * NJ + NJ];
    const int n  = hi - lo;

    for (int t = lane; t < n; t += 64)
        toks[wave][t] = btok[(size_t)b * SEQ + lo + t];
    // no barrier: same-wave LDS ordering is handled by lgkmcnt

    const uint2* e2 = (const uint2*)ebf;             // row stride EMB4 uint2s
    const bool two  = lane < (EMB4 - 64);            // lanes 0..10: second chunk
    const int  c2   = 64 + lane;

    f32x4 A = {0.f, 0.f, 0.f, 0.f};
    f32x4 B = A, C = A;
    int i = 0;
    for (; i + 4 <= n; i += 4) {
        const int4 t4 = *(const int4*)&toks[wave][i];
        const uint2 u0 = e2[(size_t)t4.x * EMB4 + lane];
        const uint2 u1 = e2[(size_t)t4.y * EMB4 + lane];
        const uint2 u2 = e2[(size_t)t4.z * EMB4 + lane];
        const uint2 u3 = e2[(size_t)t4.w * EMB4 + lane];
        A += bf4up(u0) + bf4up(u1);
        B += bf4up(u2) + bf4up(u3);
        if (two) {
            const uint2 w0 = e2[(size_t)t4.x * EMB4 + c2];
            const uint2 w1 = e2[(size_t)t4.y * EMB4 + c2];
            const uint2 w2 = e2[(size_t)t4.z * EMB4 + c2];
            const uint2 w3 = e2[(size_t)t4.w * EMB4 + c2];
            C += (bf4up(w0) + bf4up(w1)) + (bf4up(w2) + bf4up(w3));
        }
    }
    for (; i < n; ++i) {
        const int tk = toks[wave][i];
        A += bf4up(e2[(size_t)tk * EMB4 + lane]);
        if (two) C += bf4up(e2[(size_t)tk * EMB4 + c2]);
    }
    A += B;

    f32x4* dst = (f32x4*)(partial + ((size_t)x * BATCH + b) * EMB);
    dst[lane] = A;                     // 64 lanes x 16 B coalesced
    if (two) dst[c2] = C;
}

// ---------------- Kernel 3: fused combine + fc1 + relu + fc2 (R10) -----------
template<int NXT>
__global__ __launch_bounds__(512) void mlp_kernel(
    const float* __restrict__ partial, // [NXT, BATCH, EMB]
    const int* __restrict__ lengths,   // [BATCH]
    const float* __restrict__ W1,      // [EMB, HIDDEN]
    const float* __restrict__ b1,      // [HIDDEN]
    const float* __restrict__ W2,      // [HIDDEN, 2]
    const float* __restrict__ b2,      // [2]
    float* __restrict__ out)           // [BATCH, 2]
{
    __shared__ f32x4 pQ[GMLP / 4][EMB];    // 9.6 KB
    __shared__ float hsh[GMLP][HIDDEN];    // 16 KB

    const int b0  = blockIdx.x * GMLP;
    const int tid = threadIdx.x;

    float* pQf = (float*)pQ;
    for (int i = tid; i < EMB * GMLP; i += 512) {
        const int g = i / EMB;
        const int e = i - g * EMB;
        float s = 0.f;
#pragma unroll
        for (int xx = 0; xx < NXT; ++xx)
            s += partial[((size_t)xx * BATCH + b0 + g) * EMB + e];
        pQf[((g >> 2) * EMB + e) * 4 + (g & 3)] = s / (float)lengths[b0 + g];
    }
    __syncthreads();

    const int j = tid;                     // HIDDEN == blockDim
    const float bias = b1[j];
    f32x4 acc0 = {bias, bias, bias, bias};
    f32x4 acc1 = acc0;

#pragma unroll 10
    for (int e = 0; e < EMB; ++e) {
        const float w = W1[(size_t)e * HIDDEN + j];
        acc0 += pQ[0][e] * w;
        acc1 += pQ[1][e] * w;
    }
    hsh[0][j] = fmaxf(acc0.x, 0.f);
    hsh[1][j] = fmaxf(acc0.y, 0.f);
    hsh[2][j] = fmaxf(acc0.z, 0.f);
    hsh[3][j] = fmaxf(acc0.w, 0.f);
    hsh[4][j] = fmaxf(acc1.x, 0.f);
    hsh[5][j] = fmaxf(acc1.y, 0.f);
    hsh[6][j] = fmaxf(acc1.z, 0.f);
    hsh[7][j] = fmaxf(acc1.w, 0.f);
    __syncthreads();

    const int w    = tid >> 6;             // 0..7 -> batch row
    const int lane = tid & 63;
    const f32x4* W2v = (const f32x4*)W2;
    float s0 = 0.f, s1 = 0.f;
#pragma unroll
    for (int q = 0; q < 2; ++q) {
        const int cc = lane + q * 64;
        const f32x4 hv = *(const f32x4*)&hsh[w][4 * cc];
        const f32x4 wA = W2v[2 * cc + 0];
        const f32x4 wB = W2v[2 * cc + 1];
        s0 += hv.x * wA.x + hv.y * wA.z + hv.z * wB.x + hv.w * wB.z;
        s1 += hv.x * wA.y + hv.y * wA.w + hv.z * wB.y + hv.w * wB.w;
    }
#pragma unroll
    for (int off = 32; off > 0; off >>= 1) {
        s0 += __shfl_down(s0, off);
        s1 += __shfl_down(s1, off);
    }
    if (lane == 0) {
        out[(b0 + w) * 2 + 0] = s0 + b2[0];
        out[(b0 + w) * 2 + 1] = s1 + b2[1];
    }
}

// ---------------- Fallback pool (tiny ws): naive f32 gather ------------------
__global__ __launch_bounds__(320) void naive_pool(
    const int* __restrict__ text, const int* __restrict__ lengths,
    const float* __restrict__ emb, float* __restrict__ pooled)
{
    __shared__ int toks[SEQ];
    const int b = blockIdx.x;
    const int len = lengths[b];
    for (int s = threadIdx.x; s < len; s += 320)
        toks[s] = text[(size_t)s * BATCH + b];
    __syncthreads();
    const int e = threadIdx.x;
    if (e < EMB) {
        float a = 0.f;
        for (int s = 0; s < len; ++s)
            a += emb[(size_t)toks[s] * EMB + e];
        pooled[(size_t)b * EMB + e] = a;   // mlp<1> divides by len
    }
}

extern "C" void kernel_launch(void* const* d_in, const int* in_sizes, int n_in,
                              void* d_out, int out_size, void* d_ws, size_t ws_size,
                              hipStream_t stream) {
    const int*   text    = (const int*)d_in[0];
    const int*   lengths = (const int*)d_in[1];
    const float* emb     = (const float*)d_in[2];
    const float* W1      = (const float*)d_in[3];
    const float* b1      = (const float*)d_in[4];
    const float* W2      = (const float*)d_in[5];
    const float* b2      = (const float*)d_in[6];
    float*       out     = (float*)d_out;

    char* ws = (char*)d_ws;
    const size_t btokBytes = (size_t)BATCH * SEQ * sizeof(int);            // 2 MB
    const size_t boffBytes = (size_t)BATCH * (NBUK + 1) * sizeof(int);     // 132 KB
    const size_t ebfBytes  = (size_t)VOCAB * EMB * sizeof(unsigned short); // 30 MB
    const size_t poolBytes = (size_t)BATCH * EMB * sizeof(float);          // 1.2 MB

    int* btok = (int*)ws;
    int* boff = (int*)(ws + btokBytes);
    size_t off = btokBytes + boffBytes;
    off = (off + 63) & ~(size_t)63;
    unsigned short* ebf = (unsigned short*)(ws + off);
    float* partial = (float*)(ws + off + ebfBytes);

    const size_t need = off + ebfBytes + (size_t)NX * poolBytes;   // ~42 MB

    if (ws_size >= need) {
        prep_kernel<<<256 + NCONV, 256, 0, stream>>>(
            text, lengths, emb, btok, boff, ebf, 1);
        pool_kernel<<<NX * (BATCH / 4), 256, 0, stream>>>(btok, boff, ebf, partial);
        mlp_kernel<8><<<BATCH / GMLP, 512, 0, stream>>>(
            partial, lengths, W1, b1, W2, b2, out);
    } else {
        float* pooled = (float*)ws;    // [BATCH, EMB], 1.2 MB
        naive_pool<<<BATCH, 320, 0, stream>>>(text, lengths, emb, pooled);
        mlp_kernel<1><<<BATCH / GMLP, 512, 0, stream>>>(
            pooled, lengths, W1, b1, W2, b2, out);
    }
}